// Round 13
// baseline (184.277 us; speedup 1.0000x reference)
//
#include <hip/hip_runtime.h>
#include <hip/hip_bf16.h>
#include <math.h>

// Problem: B=2, N=2048, D_MODEL=1024, H=16, D_HEAD=64. fp32 in/out,
// bf16 MFMA internal (threshold is bf16-grade: 2% of max|ref|).
#define BATCH 2
#define NSEQ  2048
#define DM    1024
#define NH    16
#define DH    64
#define EPS_N 1e-6f

typedef unsigned short u16;
typedef __attribute__((ext_vector_type(8))) short short8;       // bf16x8 MFMA frag
typedef __attribute__((ext_vector_type(8))) unsigned short u16x8;
typedef __attribute__((ext_vector_type(4))) unsigned short u16x4;
typedef __attribute__((ext_vector_type(4))) float f32x4;

__device__ __forceinline__ u16 f2bf(float x) {
  __hip_bfloat16 h = __float2bfloat16(x);          // round-to-nearest-even
  return *reinterpret_cast<u16*>(&h);
}

// async 16B global->LDS (lane i lands at lds_base + 16*i)
__device__ __forceinline__ void gl_lds16(const u16* g, u16* lds_base) {
  __builtin_amdgcn_global_load_lds(
      (__attribute__((address_space(1))) void*)g,
      (__attribute__((address_space(3))) void*)lds_base, 16, 0, 0);
}

// ---------------------------------------------------------------------------
// Prep: blocks 0..1023 transpose+cast the 4 weight matrices (out[n][k] =
// bf16(in[k][n])); blocks 1024..3071 cast X fp32->bf16. grid 3072, 256 thr.
// ---------------------------------------------------------------------------
__global__ __launch_bounds__(256) void prep(
    const float* __restrict__ X,
    const float* __restrict__ w0, const float* __restrict__ w1,
    const float* __restrict__ w2, const float* __restrict__ w3,
    u16* __restrict__ Xb, u16* __restrict__ WT) {
  const int id = blockIdx.x, tid = threadIdx.x;
  if (id >= 1024) {                       // ---- cast X chunk
    size_t base = ((size_t)(id - 1024) * 256 + tid) * 8;
    float4 f0 = *(const float4*)&X[base];
    float4 f1 = *(const float4*)&X[base + 4];
    u16x8 v;
    v[0] = f2bf(f0.x); v[1] = f2bf(f0.y); v[2] = f2bf(f0.z); v[3] = f2bf(f0.w);
    v[4] = f2bf(f1.x); v[5] = f2bf(f1.y); v[6] = f2bf(f1.z); v[7] = f2bf(f1.w);
    *(u16x8*)&Xb[base] = v;
    return;
  }
  // ---- weight transpose tile
  const int z = id >> 8, xy = id & 255, bx = xy & 15, by = xy >> 4;
  const float* in = (z == 0) ? w0 : (z == 1) ? w1 : (z == 2) ? w2 : w3;
  u16* o = WT + (size_t)z * DM * DM;
  __shared__ u16 T[64][65];
  const int n0 = bx * 64, k0 = by * 64;
  #pragma unroll
  for (int i = 0; i < 4; i++) {
    int c = tid + 256 * i, row = c >> 4, col4 = c & 15;
    float4 f = *(const float4*)&in[(size_t)(k0 + row) * DM + n0 + col4 * 4];
    T[row][col4 * 4 + 0] = f2bf(f.x);
    T[row][col4 * 4 + 1] = f2bf(f.y);
    T[row][col4 * 4 + 2] = f2bf(f.z);
    T[row][col4 * 4 + 3] = f2bf(f.w);
  }
  __syncthreads();
  #pragma unroll
  for (int i = 0; i < 2; i++) {
    int c = tid + 256 * i, row = c >> 3, col8 = c & 7;
    u16x8 v;
    #pragma unroll
    for (int e = 0; e < 8; e++) v[e] = T[col8 * 8 + e][row];
    *(u16x8*)&o[(size_t)(n0 + row) * DM + k0 + col8 * 8] = v;
  }
}

// ===========================================================================
// GEMM building blocks. XOR swizzle: LDS row r holds global chunk g at slot
// g^(r&7). 256 thr, 4 waves.
// ===========================================================================
#define GEMM_STAGE_A(Aptr, koff, Adst, NSLAB_W)                                \
  do {                                                                         \
    _Pragma("unroll") for (int L = 0; L < (NSLAB_W); L++) {                    \
      int I = w * (NSLAB_W) + L;                                               \
      gl_lds16(Aptr + (size_t)(m0 + I * 8 + srow) * DM + (koff) + scol,        \
               (Adst) + I * 512);                                              \
    }                                                                          \
  } while (0)
#define GEMM_STAGE_B(Btptr, koff, Bdst, NSLAB_W)                               \
  do {                                                                         \
    _Pragma("unroll") for (int L = 0; L < (NSLAB_W); L++) {                    \
      int I = w * (NSLAB_W) + L;                                               \
      gl_lds16(Btptr + (size_t)(n0 + I * 8 + srow) * DM + (koff) + scol,       \
               (Bdst) + I * 512);                                              \
    }                                                                          \
  } while (0)

#define GEMM_COMMON_DECLS                                                      \
  const int tid = threadIdx.x, w = tid >> 6, lane = tid & 63;                  \
  const int ml = lane & 15, quad = lane >> 4;                                  \
  const int wm = w & 1, wn = w >> 1;                                           \
  const int srow = lane >> 3;                 /* 0..7 within 8-row slab */     \
  const int scol = ((lane & 7) ^ srow) * 8;   /* swizzled global chunk */

// ---------------------------------------------------------------------------
// QKV GEMM + fused L2 norm (v10 DBUF, best measured: 47.4 us fast-clock).
// 64x128 tile; per-wave 32x64 = acc[2][4]. grid (8, 64, 3), 256 thr.
// ---------------------------------------------------------------------------
__global__ __launch_bounds__(256) void gemm_qkv128(
    const u16* __restrict__ Xb, const u16* __restrict__ WT,
    u16* __restrict__ Qo, u16* __restrict__ Ko, u16* __restrict__ Vt) {
  const u16* Bt = WT + (size_t)blockIdx.z * DM * DM;
  __shared__ u16 As[2][64 * 64];
  __shared__ u16 Bs[2][128 * 64];
  GEMM_COMMON_DECLS
  const int m0 = blockIdx.y * 64, n0 = blockIdx.x * 128;
  f32x4 acc[2][4];
  #pragma unroll
  for (int mi = 0; mi < 2; mi++)
    #pragma unroll
    for (int ni = 0; ni < 4; ni++)
      #pragma unroll
      for (int e = 0; e < 4; e++) acc[mi][ni][e] = 0.f;

  GEMM_STAGE_A(Xb, 0, As[0], 2);
  GEMM_STAGE_B(Bt, 0, Bs[0], 4);
  __syncthreads();                 // buf0 ready (vmcnt drain)
  int cur = 0;
  for (int k0 = 0; k0 < DM; k0 += 64) {
    if (k0 + 64 < DM) {
      GEMM_STAGE_A(Xb, k0 + 64, As[cur ^ 1], 2);
      GEMM_STAGE_B(Bt, k0 + 64, Bs[cur ^ 1], 4);
    }
    #pragma unroll
    for (int kk = 0; kk < 64; kk += 32) {
      const int kc = kk >> 3;
      short8 am[2], bn[4];
      #pragma unroll
      for (int i = 0; i < 2; i++) {
        int ra = wm * 32 + i * 16 + ml;
        am[i] = *(const short8*)&As[cur][ra * 64 + (((quad + kc) ^ (ra & 7)) * 8)];
      }
      #pragma unroll
      for (int i = 0; i < 4; i++) {
        int rb = wn * 64 + i * 16 + ml;
        bn[i] = *(const short8*)&Bs[cur][rb * 64 + (((quad + kc) ^ (rb & 7)) * 8)];
      }
      #pragma unroll
      for (int mi = 0; mi < 2; mi++)
        #pragma unroll
        for (int ni = 0; ni < 4; ni++)
          acc[mi][ni] = __builtin_amdgcn_mfma_f32_16x16x32_bf16(
              am[mi], bn[ni], acc[mi][ni], 0, 0, 0);
    }
    __syncthreads();               // drains vmcnt(0): buf^1 ready
    cur ^= 1;
  }

  const int z = blockIdx.z;
  if (z < 2) {
    u16* OutQK = (z == 0) ? Qo : Ko;
    const float qsc = (z == 0) ? 0.125f : 1.0f;     // fold softmax 1/sqrt(64)
    const int h = (n0 >> 6) + wn;                   // head of this wave's cols
    #pragma unroll
    for (int mi = 0; mi < 2; mi++) {
      int mrow0 = m0 + wm * 32 + mi * 16 + quad * 4;
      int b = mrow0 >> 11, tok0 = mrow0 & (NSEQ - 1);
      #pragma unroll
      for (int r = 0; r < 4; r++) {
        float ss = 0.f;
        #pragma unroll
        for (int ni = 0; ni < 4; ni++) ss += acc[mi][ni][r] * acc[mi][ni][r];
        ss += __shfl_xor(ss, 1, 64);
        ss += __shfl_xor(ss, 2, 64);
        ss += __shfl_xor(ss, 4, 64);
        ss += __shfl_xor(ss, 8, 64);    // sum over the 16 ml lanes (full row)
        float sc = qsc / (sqrtf(ss) + EPS_N);
        #pragma unroll
        for (int ni = 0; ni < 4; ni++)
          OutQK[((size_t)(b * NH + h) * NSEQ + tok0 + r) * DH + ni * 16 + ml] =
              f2bf(acc[mi][ni][r] * sc);
      }
    }
  } else {
    #pragma unroll
    for (int mi = 0; mi < 2; mi++) {
      int mrow0 = m0 + wm * 32 + mi * 16 + quad * 4;
      int b = mrow0 >> 11, tok0 = mrow0 & (NSEQ - 1);
      #pragma unroll
      for (int ni = 0; ni < 4; ni++) {
        int n = n0 + wn * 64 + ni * 16 + ml;
        int h = n >> 6, d = n & 63;
        u16x4 pk;
        #pragma unroll
        for (int r = 0; r < 4; r++) pk[r] = f2bf(acc[mi][ni][r]);
        *(u16x4*)&Vt[((size_t)(b * NH + h) * DH + d) * NSEQ + tok0] = pk;
      }
    }
  }
}

// ---------------------------------------------------------------------------
// Output projection (v13): 64x64 tile, DBUF, grid (16, 64) = 1024 blocks =
// 4 blocks/CU (16 waves/CU) — the occupancy regime where dbuf was measured
// to help qkv (12-24 waves/CU). v12's sbuf at the same occupancy paid 16
// exposed per-K-step drains. LDS 32 KB (2x(8+8)), still 4 blocks/CU.
// Per-wave 32x32 = acc[2][2]; each wave stages 2 A-slabs + 2 B-slabs.
// ---------------------------------------------------------------------------
__global__ __launch_bounds__(256) void gemm_proj128(
    const u16* __restrict__ A, const u16* __restrict__ BtW,
    const float* __restrict__ bias, float* __restrict__ out) {
  __shared__ u16 As[2][64 * 64];
  __shared__ u16 Bs[2][64 * 64];
  GEMM_COMMON_DECLS
  const int m0 = blockIdx.y * 64, n0 = blockIdx.x * 64;
  f32x4 acc[2][2];
  #pragma unroll
  for (int mi = 0; mi < 2; mi++)
    #pragma unroll
    for (int ni = 0; ni < 2; ni++)
      #pragma unroll
      for (int e = 0; e < 4; e++) acc[mi][ni][e] = 0.f;

  GEMM_STAGE_A(A, 0, As[0], 2);
  GEMM_STAGE_B(BtW, 0, Bs[0], 2);
  __syncthreads();                 // buf0 ready (vmcnt drain)
  int cur = 0;
  for (int k0 = 0; k0 < DM; k0 += 64) {
    if (k0 + 64 < DM) {
      GEMM_STAGE_A(A, k0 + 64, As[cur ^ 1], 2);
      GEMM_STAGE_B(BtW, k0 + 64, Bs[cur ^ 1], 2);
    }
    #pragma unroll
    for (int kk = 0; kk < 64; kk += 32) {
      const int kc = kk >> 3;
      short8 am[2], bn[2];
      #pragma unroll
      for (int i = 0; i < 2; i++) {
        int ra = wm * 32 + i * 16 + ml;
        am[i] = *(const short8*)&As[cur][ra * 64 + (((quad + kc) ^ (ra & 7)) * 8)];
      }
      #pragma unroll
      for (int i = 0; i < 2; i++) {
        int rb = wn * 32 + i * 16 + ml;
        bn[i] = *(const short8*)&Bs[cur][rb * 64 + (((quad + kc) ^ (rb & 7)) * 8)];
      }
      #pragma unroll
      for (int mi = 0; mi < 2; mi++)
        #pragma unroll
        for (int ni = 0; ni < 2; ni++)
          acc[mi][ni] = __builtin_amdgcn_mfma_f32_16x16x32_bf16(
              am[mi], bn[ni], acc[mi][ni], 0, 0, 0);
    }
    __syncthreads();               // drains vmcnt(0): buf^1 ready
    cur ^= 1;
  }
  #pragma unroll
  for (int ni = 0; ni < 2; ni++) {
    int n = n0 + wn * 32 + ni * 16 + ml;
    float bz = bias[n];
    #pragma unroll
    for (int mi = 0; mi < 2; mi++) {
      int mrow0 = m0 + wm * 32 + mi * 16 + quad * 4;
      #pragma unroll
      for (int r = 0; r < 4; r++)
        out[(size_t)(mrow0 + r) * DM + n] = acc[mi][ni][r] + bz;
    }
  }
}

// ---------------------------------------------------------------------------
// MFMA flash attention, causal, NO online max (|score|<=0.125 by L2 norm) ->
// O and l are ADDITIVE partials: split keys across waves, combine once/phase.
//
// v6 flash (best measured): QBLK=64, KVBLK=64, 512 thr = 8 waves (4 q-waves
// wq x 2 key-halves wk). Grid (bh=32, pairY=16); pair {y, 31-y} -> 33
// tiles/block balanced. XCD = flat%8 = bh%8 (4 heads' K/V per XCD, L2-fit).
// Reg-prefetch one tile ahead; XOR-swizzled LDS. LDS ~43.8 KB, 3 blocks/CU.
// ---------------------------------------------------------------------------
__global__ __launch_bounds__(512) void flash_attn(
    const u16* __restrict__ Qb, const u16* __restrict__ Kb,
    const u16* __restrict__ Vt, u16* __restrict__ vhat) {
  const int tid = threadIdx.x, w = tid >> 6, lane = tid & 63;
  const int ml = lane & 15, quad = lane >> 4;
  const int wq = w & 3, wk = w >> 2;
  const int bh = blockIdx.x;                  // 0..31 (= b*NH + h)
  const int bb = bh >> 4, hb = bh & 15;
  const int pairY = blockIdx.y;               // 0..15
  const u16* Qh = Qb + (size_t)bh * NSEQ * DH;
  const u16* Kh = Kb + (size_t)bh * NSEQ * DH;
  const u16* Vth = Vt + (size_t)bh * DH * NSEQ;

  __shared__ u16 Ks [64 * 64];     // K[key][d], chunk s of row r = global s^r
  __shared__ u16 VsT[64 * 64];     // V^T[d][key], same scheme
  __shared__ u16 Ps [8][16][40];   // per-wave P[q16][key32] (C->A transform)
  __shared__ float Os[4][16][66];  // wk0's partial O [wq][q][d]
  __shared__ float Ls[4][16];      // wk0's partial l [wq][q]

  const int srow8 = lane >> 3;                // 0..7 row within slab
  const int sch   = lane & 7;                 // linear global 16B chunk
  const int sslot = sch ^ srow8;              // swizzled LDS 16B slot

  for (int ph = 0; ph < 2; ph++) {
    const int qb64 = ph ? (31 - pairY) : pairY;
    const int q0 = qb64 * 64;
    const int ntiles = qb64 + 1;

    // Q A-frags for this wave's 16 rows: A[m=ml][k=quad*8+j]
    short8 aq[2];
    #pragma unroll
    for (int c = 0; c < 2; c++)
      aq[c] = *(const short8*)&Qh[(size_t)(q0 + wq * 16 + ml) * DH + c * 32 + quad * 8];

    f32x4 oacc[4];
    #pragma unroll
    for (int n = 0; n < 4; n++)
      #pragma unroll
      for (int e = 0; e < 4; e++) oacc[n][e] = 0.f;
    float l_[4] = {0.f, 0.f, 0.f, 0.f};

    // prologue: prefetch tile 0's K/V slab into regs
    u16x8 kreg, vreg;
    kreg = *(const u16x8*)&Kh[(size_t)(w * 8 + srow8) * DH + sch * 8];
    vreg = *(const u16x8*)&Vth[(size_t)(w * 8 + srow8) * NSEQ + sch * 8];

    for (int t = 0; t < ntiles; t++) {
      const int j0 = t * 64;
      __syncthreads();            // A: all waves done with prev tile's LDS;
                                  //    implicit vmcnt(0) = this tile's regs ok
      *(u16x8*)&Ks [(w * 8 + srow8) * 64 + sslot * 8] = kreg;
      *(u16x8*)&VsT[(w * 8 + srow8) * 64 + sslot * 8] = vreg;
      __syncthreads();            // B: staged tiles visible to all waves

      // prefetch NEXT tile into regs — in flight during this tile's compute
      if (t + 1 < ntiles) {
        const int j1 = j0 + 64;
        kreg = *(const u16x8*)&Kh[(size_t)(j1 + w * 8 + srow8) * DH + sch * 8];
        vreg = *(const u16x8*)&Vth[(size_t)(w * 8 + srow8) * NSEQ + j1 + sch * 8];
      }

      // S (16q x 32k): B-frag = K[key = wk*32 + n*16+ml][d = c*32+quad*8+j]
      f32x4 sacc[2];
      #pragma unroll
      for (int n = 0; n < 2; n++)
        #pragma unroll
        for (int e = 0; e < 4; e++) sacc[n][e] = 0.f;
      #pragma unroll
      for (int c = 0; c < 2; c++)
        #pragma unroll
        for (int n = 0; n < 2; n++) {
          int kr = wk * 32 + n * 16 + ml;
          short8 bf = *(const short8*)&Ks[kr * 64 + (((c * 4 + quad) ^ (kr & 7)) * 8)];
          sacc[n] = __builtin_amdgcn_mfma_f32_16x16x32_bf16(aq[c], bf, sacc[n], 0, 0, 0);
        }

      // p = exp(s), causal-masked on the last tile. C-layout: col=ml(key),
      // row=quad*4+r (q).
      const bool lastt = (t == ntiles - 1);
      float p[2][4];
      #pragma unroll
      for (int n = 0; n < 2; n++) {
        int j = j0 + wk * 32 + n * 16 + ml;
        #pragma unroll
        for (int r = 0; r < 4; r++) {
          int q = q0 + wq * 16 + quad * 4 + r;
          float e = __expf(sacc[n][r]);
          p[n][r] = (lastt && j > q) ? 0.f : e;
          l_[r] += p[n][r];
        }
      }

      // P -> per-wave LDS (C->A layout; same-wave ordering via lgkmcnt)
      #pragma unroll
      for (int n = 0; n < 2; n++)
        #pragma unroll
        for (int r = 0; r < 4; r++)
          Ps[w][quad * 4 + r][n * 16 + ml] = f2bf(p[n][r]);

      // O += P·V over this wave's 32 keys: A = P[q=ml][k=quad*8+j],
      // B = V^T[d = n*16+ml][key = wk*32 + quad*8+j]
      short8 ap = *(const short8*)&Ps[w][ml][quad * 8];
      #pragma unroll
      for (int n = 0; n < 4; n++) {
        int dr = n * 16 + ml;
        short8 bv = *(const short8*)&VsT[dr * 64 + (((wk * 4 + quad) ^ (dr & 7)) * 8)];
        oacc[n] = __builtin_amdgcn_mfma_f32_16x16x32_bf16(ap, bv, oacc[n], 0, 0, 0);
      }
    }

    // combine the two key-halves (additive: no max rescaling exists)
    float lred[4];
    #pragma unroll
    for (int r = 0; r < 4; r++) {
      float lv = l_[r];
      lv += __shfl_xor(lv, 1, 64);
      lv += __shfl_xor(lv, 2, 64);
      lv += __shfl_xor(lv, 4, 64);
      lv += __shfl_xor(lv, 8, 64);
      lred[r] = lv;                 // per (quad,r): sum over this wave's keys
    }
    if (wk == 0) {
      #pragma unroll
      for (int n = 0; n < 4; n++)
        #pragma unroll
        for (int r = 0; r < 4; r++)
          Os[wq][quad * 4 + r][n * 16 + ml] = oacc[n][r];
      if (ml == 0) {
        #pragma unroll
        for (int r = 0; r < 4; r++) Ls[wq][quad * 4 + r] = lred[r];
      }
    }
    __syncthreads();
    if (wk == 1) {
      #pragma unroll
      for (int r = 0; r < 4; r++) {
        float inv = 1.f / (lred[r] + Ls[wq][quad * 4 + r]);
        int q = q0 + wq * 16 + quad * 4 + r;
        #pragma unroll
        for (int n = 0; n < 4; n++) {
          float o = oacc[n][r] + Os[wq][quad * 4 + r][n * 16 + ml];
          vhat[((size_t)(bb * NSEQ + q)) * DM + hb * DH + n * 16 + ml] =
              f2bf(o * inv);
        }
      }
    }
    // protect Os/Ls (and Ks/VsT) reuse by the next phase
    __syncthreads();
  }
}

// ---------------------------------------------------------------------------
extern "C" void kernel_launch(void* const* d_in, const int* in_sizes, int n_in,
                              void* d_out, int out_size, void* d_ws, size_t ws_size,
                              hipStream_t stream) {
  const float* X  = (const float*)d_in[0];
  const float* Wq = (const float*)d_in[1];
  const float* Wk = (const float*)d_in[2];
  const float* Wv = (const float*)d_in[3];
  const float* Wo = (const float*)d_in[4];
  const float* bo = (const float*)d_in[5];
  float* out = (float*)d_out;

  // ws (all bf16, 8 MB each): Qb | Kb | Vt[B,H,DH,N] | {Xb then vhat, aliased}
  // | WT (4 transposed weights, 8 MB total) = 40 MB
  const size_t NE = (size_t)BATCH * NSEQ * DM;   // 4,194,304
  u16* Qb   = (u16*)d_ws;
  u16* Kb   = Qb + NE;
  u16* Vt   = Kb + NE;
  u16* XbVh = Vt + NE;                           // Xb / vhat (disjoint lifetimes)
  u16* WT   = XbVh + NE;

  prep        <<<dim3(3072),      256, 0, stream>>>(X, Wq, Wk, Wv, Wo, XbVh, WT);
  gemm_qkv128 <<<dim3(8, 64, 3),  256, 0, stream>>>(XbVh, WT, Qb, Kb, Vt);
  flash_attn  <<<dim3(32, 16),    512, 0, stream>>>(Qb, Kb, Vt, XbVh);
  gemm_proj128<<<dim3(16, 64),    256, 0, stream>>>(XbVh, WT + 3 * (size_t)DM * DM,
                                                    bo, out);
}

// Round 14
// 179.602 us; speedup vs baseline: 1.0260x; 1.0260x over previous
//
#include <hip/hip_runtime.h>
#include <hip/hip_bf16.h>
#include <math.h>

// Problem: B=2, N=2048, D_MODEL=1024, H=16, D_HEAD=64. fp32 in/out,
// bf16 MFMA internal (threshold is bf16-grade: 2% of max|ref|).
//
// FINAL (v14 = v12, the measured best: 180.6 us):
//  - prep: weight transpose + X cast (BW-bound)
//  - qkv: 64x128 DBUF 2-phase GEMM (47.4 us, MfmaUtil ~20%, conflicts 0)
//  - flash: QBLK=64/KVBLK=64, 8 waves, reg-prefetch + XOR-swizzle (3 blk/CU)
//  - proj: 64x64 SBUF at 4 blk/CU (dbuf measured WORSE for proj at both 8
//    and 16 waves/CU — only pays when MFMA/K-step >= ~16/wave, v13 A/B)
#define BATCH 2
#define NSEQ  2048
#define DM    1024
#define NH    16
#define DH    64
#define EPS_N 1e-6f

typedef unsigned short u16;
typedef __attribute__((ext_vector_type(8))) short short8;       // bf16x8 MFMA frag
typedef __attribute__((ext_vector_type(8))) unsigned short u16x8;
typedef __attribute__((ext_vector_type(4))) unsigned short u16x4;
typedef __attribute__((ext_vector_type(4))) float f32x4;

__device__ __forceinline__ u16 f2bf(float x) {
  __hip_bfloat16 h = __float2bfloat16(x);          // round-to-nearest-even
  return *reinterpret_cast<u16*>(&h);
}

// async 16B global->LDS (lane i lands at lds_base + 16*i)
__device__ __forceinline__ void gl_lds16(const u16* g, u16* lds_base) {
  __builtin_amdgcn_global_load_lds(
      (__attribute__((address_space(1))) void*)g,
      (__attribute__((address_space(3))) void*)lds_base, 16, 0, 0);
}

// ---------------------------------------------------------------------------
// Prep: blocks 0..1023 transpose+cast the 4 weight matrices (out[n][k] =
// bf16(in[k][n])); blocks 1024..3071 cast X fp32->bf16. grid 3072, 256 thr.
// ---------------------------------------------------------------------------
__global__ __launch_bounds__(256) void prep(
    const float* __restrict__ X,
    const float* __restrict__ w0, const float* __restrict__ w1,
    const float* __restrict__ w2, const float* __restrict__ w3,
    u16* __restrict__ Xb, u16* __restrict__ WT) {
  const int id = blockIdx.x, tid = threadIdx.x;
  if (id >= 1024) {                       // ---- cast X chunk
    size_t base = ((size_t)(id - 1024) * 256 + tid) * 8;
    float4 f0 = *(const float4*)&X[base];
    float4 f1 = *(const float4*)&X[base + 4];
    u16x8 v;
    v[0] = f2bf(f0.x); v[1] = f2bf(f0.y); v[2] = f2bf(f0.z); v[3] = f2bf(f0.w);
    v[4] = f2bf(f1.x); v[5] = f2bf(f1.y); v[6] = f2bf(f1.z); v[7] = f2bf(f1.w);
    *(u16x8*)&Xb[base] = v;
    return;
  }
  // ---- weight transpose tile
  const int z = id >> 8, xy = id & 255, bx = xy & 15, by = xy >> 4;
  const float* in = (z == 0) ? w0 : (z == 1) ? w1 : (z == 2) ? w2 : w3;
  u16* o = WT + (size_t)z * DM * DM;
  __shared__ u16 T[64][65];
  const int n0 = bx * 64, k0 = by * 64;
  #pragma unroll
  for (int i = 0; i < 4; i++) {
    int c = tid + 256 * i, row = c >> 4, col4 = c & 15;
    float4 f = *(const float4*)&in[(size_t)(k0 + row) * DM + n0 + col4 * 4];
    T[row][col4 * 4 + 0] = f2bf(f.x);
    T[row][col4 * 4 + 1] = f2bf(f.y);
    T[row][col4 * 4 + 2] = f2bf(f.z);
    T[row][col4 * 4 + 3] = f2bf(f.w);
  }
  __syncthreads();
  #pragma unroll
  for (int i = 0; i < 2; i++) {
    int c = tid + 256 * i, row = c >> 3, col8 = c & 7;
    u16x8 v;
    #pragma unroll
    for (int e = 0; e < 8; e++) v[e] = T[col8 * 8 + e][row];
    *(u16x8*)&o[(size_t)(n0 + row) * DM + k0 + col8 * 8] = v;
  }
}

// ===========================================================================
// GEMM building blocks. XOR swizzle: LDS row r holds global chunk g at slot
// g^(r&7). 256 thr, 4 waves.
// ===========================================================================
#define GEMM_STAGE_A(Aptr, koff, Adst, NSLAB_W)                                \
  do {                                                                         \
    _Pragma("unroll") for (int L = 0; L < (NSLAB_W); L++) {                    \
      int I = w * (NSLAB_W) + L;                                               \
      gl_lds16(Aptr + (size_t)(m0 + I * 8 + srow) * DM + (koff) + scol,        \
               (Adst) + I * 512);                                              \
    }                                                                          \
  } while (0)
#define GEMM_STAGE_B(Btptr, koff, Bdst, NSLAB_W)                               \
  do {                                                                         \
    _Pragma("unroll") for (int L = 0; L < (NSLAB_W); L++) {                    \
      int I = w * (NSLAB_W) + L;                                               \
      gl_lds16(Btptr + (size_t)(n0 + I * 8 + srow) * DM + (koff) + scol,       \
               (Bdst) + I * 512);                                              \
    }                                                                          \
  } while (0)

#define GEMM_COMMON_DECLS                                                      \
  const int tid = threadIdx.x, w = tid >> 6, lane = tid & 63;                  \
  const int ml = lane & 15, quad = lane >> 4;                                  \
  const int wm = w & 1, wn = w >> 1;                                           \
  const int srow = lane >> 3;                 /* 0..7 within 8-row slab */     \
  const int scol = ((lane & 7) ^ srow) * 8;   /* swizzled global chunk */

// ---------------------------------------------------------------------------
// QKV GEMM + fused L2 norm (DBUF, best measured: 47.4 us fast-clock).
// 64x128 tile; per-wave 32x64 = acc[2][4]. grid (8, 64, 3), 256 thr.
// ---------------------------------------------------------------------------
__global__ __launch_bounds__(256) void gemm_qkv128(
    const u16* __restrict__ Xb, const u16* __restrict__ WT,
    u16* __restrict__ Qo, u16* __restrict__ Ko, u16* __restrict__ Vt) {
  const u16* Bt = WT + (size_t)blockIdx.z * DM * DM;
  __shared__ u16 As[2][64 * 64];
  __shared__ u16 Bs[2][128 * 64];
  GEMM_COMMON_DECLS
  const int m0 = blockIdx.y * 64, n0 = blockIdx.x * 128;
  f32x4 acc[2][4];
  #pragma unroll
  for (int mi = 0; mi < 2; mi++)
    #pragma unroll
    for (int ni = 0; ni < 4; ni++)
      #pragma unroll
      for (int e = 0; e < 4; e++) acc[mi][ni][e] = 0.f;

  GEMM_STAGE_A(Xb, 0, As[0], 2);
  GEMM_STAGE_B(Bt, 0, Bs[0], 4);
  __syncthreads();                 // buf0 ready (vmcnt drain)
  int cur = 0;
  for (int k0 = 0; k0 < DM; k0 += 64) {
    if (k0 + 64 < DM) {
      GEMM_STAGE_A(Xb, k0 + 64, As[cur ^ 1], 2);
      GEMM_STAGE_B(Bt, k0 + 64, Bs[cur ^ 1], 4);
    }
    #pragma unroll
    for (int kk = 0; kk < 64; kk += 32) {
      const int kc = kk >> 3;
      short8 am[2], bn[4];
      #pragma unroll
      for (int i = 0; i < 2; i++) {
        int ra = wm * 32 + i * 16 + ml;
        am[i] = *(const short8*)&As[cur][ra * 64 + (((quad + kc) ^ (ra & 7)) * 8)];
      }
      #pragma unroll
      for (int i = 0; i < 4; i++) {
        int rb = wn * 64 + i * 16 + ml;
        bn[i] = *(const short8*)&Bs[cur][rb * 64 + (((quad + kc) ^ (rb & 7)) * 8)];
      }
      #pragma unroll
      for (int mi = 0; mi < 2; mi++)
        #pragma unroll
        for (int ni = 0; ni < 4; ni++)
          acc[mi][ni] = __builtin_amdgcn_mfma_f32_16x16x32_bf16(
              am[mi], bn[ni], acc[mi][ni], 0, 0, 0);
    }
    __syncthreads();               // drains vmcnt(0): buf^1 ready
    cur ^= 1;
  }

  const int z = blockIdx.z;
  if (z < 2) {
    u16* OutQK = (z == 0) ? Qo : Ko;
    const float qsc = (z == 0) ? 0.125f : 1.0f;     // fold softmax 1/sqrt(64)
    const int h = (n0 >> 6) + wn;                   // head of this wave's cols
    #pragma unroll
    for (int mi = 0; mi < 2; mi++) {
      int mrow0 = m0 + wm * 32 + mi * 16 + quad * 4;
      int b = mrow0 >> 11, tok0 = mrow0 & (NSEQ - 1);
      #pragma unroll
      for (int r = 0; r < 4; r++) {
        float ss = 0.f;
        #pragma unroll
        for (int ni = 0; ni < 4; ni++) ss += acc[mi][ni][r] * acc[mi][ni][r];
        ss += __shfl_xor(ss, 1, 64);
        ss += __shfl_xor(ss, 2, 64);
        ss += __shfl_xor(ss, 4, 64);
        ss += __shfl_xor(ss, 8, 64);    // sum over the 16 ml lanes (full row)
        float sc = qsc / (sqrtf(ss) + EPS_N);
        #pragma unroll
        for (int ni = 0; ni < 4; ni++)
          OutQK[((size_t)(b * NH + h) * NSEQ + tok0 + r) * DH + ni * 16 + ml] =
              f2bf(acc[mi][ni][r] * sc);
      }
    }
  } else {
    #pragma unroll
    for (int mi = 0; mi < 2; mi++) {
      int mrow0 = m0 + wm * 32 + mi * 16 + quad * 4;
      int b = mrow0 >> 11, tok0 = mrow0 & (NSEQ - 1);
      #pragma unroll
      for (int ni = 0; ni < 4; ni++) {
        int n = n0 + wn * 64 + ni * 16 + ml;
        int h = n >> 6, d = n & 63;
        u16x4 pk;
        #pragma unroll
        for (int r = 0; r < 4; r++) pk[r] = f2bf(acc[mi][ni][r]);
        *(u16x4*)&Vt[((size_t)(b * NH + h) * DH + d) * NSEQ + tok0] = pk;
      }
    }
  }
}

// ---------------------------------------------------------------------------
// Output projection: 64x64 tile, SBUF, grid (16, 64) = 1024 blocks =
// 4 blocks/CU (16 waves). dbuf measured worse here at both 8 and 16 waves/CU
// (v10/v13 A/B): with only 8 MFMA/K-step per wave, dbuf's DMA/ds_read LDS
// contention isn't covered; phase-separated staging wins.
// Per-wave 32x32 = acc[2][2]; As/Bs 8 KB each (16 KB LDS).
// ---------------------------------------------------------------------------
__global__ __launch_bounds__(256) void gemm_proj128(
    const u16* __restrict__ A, const u16* __restrict__ BtW,
    const float* __restrict__ bias, float* __restrict__ out) {
  __shared__ u16 As[64 * 64];
  __shared__ u16 Bs[64 * 64];
  GEMM_COMMON_DECLS
  const int m0 = blockIdx.y * 64, n0 = blockIdx.x * 64;
  f32x4 acc[2][2];
  #pragma unroll
  for (int mi = 0; mi < 2; mi++)
    #pragma unroll
    for (int ni = 0; ni < 2; ni++)
      #pragma unroll
      for (int e = 0; e < 4; e++) acc[mi][ni][e] = 0.f;
  for (int k0 = 0; k0 < DM; k0 += 64) {
    __syncthreads();
    GEMM_STAGE_A(A, k0, As, 2);
    GEMM_STAGE_B(BtW, k0, Bs, 2);
    __syncthreads();
    #pragma unroll
    for (int kk = 0; kk < 64; kk += 32) {
      const int kc = kk >> 3;
      short8 am[2], bn[2];
      #pragma unroll
      for (int i = 0; i < 2; i++) {
        int ra = wm * 32 + i * 16 + ml;
        am[i] = *(const short8*)&As[ra * 64 + (((quad + kc) ^ (ra & 7)) * 8)];
      }
      #pragma unroll
      for (int i = 0; i < 2; i++) {
        int rb = wn * 32 + i * 16 + ml;
        bn[i] = *(const short8*)&Bs[rb * 64 + (((quad + kc) ^ (rb & 7)) * 8)];
      }
      #pragma unroll
      for (int mi = 0; mi < 2; mi++)
        #pragma unroll
        for (int ni = 0; ni < 2; ni++)
          acc[mi][ni] = __builtin_amdgcn_mfma_f32_16x16x32_bf16(
              am[mi], bn[ni], acc[mi][ni], 0, 0, 0);
    }
  }
  #pragma unroll
  for (int ni = 0; ni < 2; ni++) {
    int n = n0 + wn * 32 + ni * 16 + ml;
    float bz = bias[n];
    #pragma unroll
    for (int mi = 0; mi < 2; mi++) {
      int mrow0 = m0 + wm * 32 + mi * 16 + quad * 4;
      #pragma unroll
      for (int r = 0; r < 4; r++)
        out[(size_t)(mrow0 + r) * DM + n] = acc[mi][ni][r] + bz;
    }
  }
}

// ---------------------------------------------------------------------------
// MFMA flash attention, causal, NO online max (|score|<=0.125 by L2 norm) ->
// O and l are ADDITIVE partials: split keys across waves, combine once/phase.
//
// Best measured config: QBLK=64, KVBLK=64, 512 thr = 8 waves (4 q-waves wq
// x 2 key-halves wk). Grid (bh=32, pairY=16); pair {y, 31-y} -> 33
// tiles/block balanced. XCD = flat%8 = bh%8 (4 heads' K/V per XCD, L2-fit).
// Reg-prefetch one tile ahead; XOR-swizzled LDS. LDS ~43.8 KB, 3 blocks/CU.
// ---------------------------------------------------------------------------
__global__ __launch_bounds__(512) void flash_attn(
    const u16* __restrict__ Qb, const u16* __restrict__ Kb,
    const u16* __restrict__ Vt, u16* __restrict__ vhat) {
  const int tid = threadIdx.x, w = tid >> 6, lane = tid & 63;
  const int ml = lane & 15, quad = lane >> 4;
  const int wq = w & 3, wk = w >> 2;
  const int bh = blockIdx.x;                  // 0..31 (= b*NH + h)
  const int bb = bh >> 4, hb = bh & 15;
  const int pairY = blockIdx.y;               // 0..15
  const u16* Qh = Qb + (size_t)bh * NSEQ * DH;
  const u16* Kh = Kb + (size_t)bh * NSEQ * DH;
  const u16* Vth = Vt + (size_t)bh * DH * NSEQ;

  __shared__ u16 Ks [64 * 64];     // K[key][d], chunk s of row r = global s^r
  __shared__ u16 VsT[64 * 64];     // V^T[d][key], same scheme
  __shared__ u16 Ps [8][16][40];   // per-wave P[q16][key32] (C->A transform)
  __shared__ float Os[4][16][66];  // wk0's partial O [wq][q][d]
  __shared__ float Ls[4][16];      // wk0's partial l [wq][q]

  const int srow8 = lane >> 3;                // 0..7 row within slab
  const int sch   = lane & 7;                 // linear global 16B chunk
  const int sslot = sch ^ srow8;              // swizzled LDS 16B slot

  for (int ph = 0; ph < 2; ph++) {
    const int qb64 = ph ? (31 - pairY) : pairY;
    const int q0 = qb64 * 64;
    const int ntiles = qb64 + 1;

    // Q A-frags for this wave's 16 rows: A[m=ml][k=quad*8+j]
    short8 aq[2];
    #pragma unroll
    for (int c = 0; c < 2; c++)
      aq[c] = *(const short8*)&Qh[(size_t)(q0 + wq * 16 + ml) * DH + c * 32 + quad * 8];

    f32x4 oacc[4];
    #pragma unroll
    for (int n = 0; n < 4; n++)
      #pragma unroll
      for (int e = 0; e < 4; e++) oacc[n][e] = 0.f;
    float l_[4] = {0.f, 0.f, 0.f, 0.f};

    // prologue: prefetch tile 0's K/V slab into regs
    u16x8 kreg, vreg;
    kreg = *(const u16x8*)&Kh[(size_t)(w * 8 + srow8) * DH + sch * 8];
    vreg = *(const u16x8*)&Vth[(size_t)(w * 8 + srow8) * NSEQ + sch * 8];

    for (int t = 0; t < ntiles; t++) {
      const int j0 = t * 64;
      __syncthreads();            // A: all waves done with prev tile's LDS;
                                  //    implicit vmcnt(0) = this tile's regs ok
      *(u16x8*)&Ks [(w * 8 + srow8) * 64 + sslot * 8] = kreg;
      *(u16x8*)&VsT[(w * 8 + srow8) * 64 + sslot * 8] = vreg;
      __syncthreads();            // B: staged tiles visible to all waves

      // prefetch NEXT tile into regs — in flight during this tile's compute
      if (t + 1 < ntiles) {
        const int j1 = j0 + 64;
        kreg = *(const u16x8*)&Kh[(size_t)(j1 + w * 8 + srow8) * DH + sch * 8];
        vreg = *(const u16x8*)&Vth[(size_t)(w * 8 + srow8) * NSEQ + j1 + sch * 8];
      }

      // S (16q x 32k): B-frag = K[key = wk*32 + n*16+ml][d = c*32+quad*8+j]
      f32x4 sacc[2];
      #pragma unroll
      for (int n = 0; n < 2; n++)
        #pragma unroll
        for (int e = 0; e < 4; e++) sacc[n][e] = 0.f;
      #pragma unroll
      for (int c = 0; c < 2; c++)
        #pragma unroll
        for (int n = 0; n < 2; n++) {
          int kr = wk * 32 + n * 16 + ml;
          short8 bf = *(const short8*)&Ks[kr * 64 + (((c * 4 + quad) ^ (kr & 7)) * 8)];
          sacc[n] = __builtin_amdgcn_mfma_f32_16x16x32_bf16(aq[c], bf, sacc[n], 0, 0, 0);
        }

      // p = exp(s), causal-masked on the last tile. C-layout: col=ml(key),
      // row=quad*4+r (q).
      const bool lastt = (t == ntiles - 1);
      float p[2][4];
      #pragma unroll
      for (int n = 0; n < 2; n++) {
        int j = j0 + wk * 32 + n * 16 + ml;
        #pragma unroll
        for (int r = 0; r < 4; r++) {
          int q = q0 + wq * 16 + quad * 4 + r;
          float e = __expf(sacc[n][r]);
          p[n][r] = (lastt && j > q) ? 0.f : e;
          l_[r] += p[n][r];
        }
      }

      // P -> per-wave LDS (C->A layout; same-wave ordering via lgkmcnt)
      #pragma unroll
      for (int n = 0; n < 2; n++)
        #pragma unroll
        for (int r = 0; r < 4; r++)
          Ps[w][quad * 4 + r][n * 16 + ml] = f2bf(p[n][r]);

      // O += P·V over this wave's 32 keys: A = P[q=ml][k=quad*8+j],
      // B = V^T[d = n*16+ml][key = wk*32 + quad*8+j]
      short8 ap = *(const short8*)&Ps[w][ml][quad * 8];
      #pragma unroll
      for (int n = 0; n < 4; n++) {
        int dr = n * 16 + ml;
        short8 bv = *(const short8*)&VsT[dr * 64 + (((wk * 4 + quad) ^ (dr & 7)) * 8)];
        oacc[n] = __builtin_amdgcn_mfma_f32_16x16x32_bf16(ap, bv, oacc[n], 0, 0, 0);
      }
    }

    // combine the two key-halves (additive: no max rescaling exists)
    float lred[4];
    #pragma unroll
    for (int r = 0; r < 4; r++) {
      float lv = l_[r];
      lv += __shfl_xor(lv, 1, 64);
      lv += __shfl_xor(lv, 2, 64);
      lv += __shfl_xor(lv, 4, 64);
      lv += __shfl_xor(lv, 8, 64);
      lred[r] = lv;                 // per (quad,r): sum over this wave's keys
    }
    if (wk == 0) {
      #pragma unroll
      for (int n = 0; n < 4; n++)
        #pragma unroll
        for (int r = 0; r < 4; r++)
          Os[wq][quad * 4 + r][n * 16 + ml] = oacc[n][r];
      if (ml == 0) {
        #pragma unroll
        for (int r = 0; r < 4; r++) Ls[wq][quad * 4 + r] = lred[r];
      }
    }
    __syncthreads();
    if (wk == 1) {
      #pragma unroll
      for (int r = 0; r < 4; r++) {
        float inv = 1.f / (lred[r] + Ls[wq][quad * 4 + r]);
        int q = q0 + wq * 16 + quad * 4 + r;
        #pragma unroll
        for (int n = 0; n < 4; n++) {
          float o = oacc[n][r] + Os[wq][quad * 4 + r][n * 16 + ml];
          vhat[((size_t)(bb * NSEQ + q)) * DM + hb * DH + n * 16 + ml] =
              f2bf(o * inv);
        }
      }
    }
    // protect Os/Ls (and Ks/VsT) reuse by the next phase
    __syncthreads();
  }
}

// ---------------------------------------------------------------------------
extern "C" void kernel_launch(void* const* d_in, const int* in_sizes, int n_in,
                              void* d_out, int out_size, void* d_ws, size_t ws_size,
                              hipStream_t stream) {
  const float* X  = (const float*)d_in[0];
  const float* Wq = (const float*)d_in[1];
  const float* Wk = (const float*)d_in[2];
  const float* Wv = (const float*)d_in[3];
  const float* Wo = (const float*)d_in[4];
  const float* bo = (const float*)d_in[5];
  float* out = (float*)d_out;

  // ws (all bf16, 8 MB each): Qb | Kb | Vt[B,H,DH,N] | {Xb then vhat, aliased}
  // | WT (4 transposed weights, 8 MB total) = 40 MB
  const size_t NE = (size_t)BATCH * NSEQ * DM;   // 4,194,304
  u16* Qb   = (u16*)d_ws;
  u16* Kb   = Qb + NE;
  u16* Vt   = Kb + NE;
  u16* XbVh = Vt + NE;                           // Xb / vhat (disjoint lifetimes)
  u16* WT   = XbVh + NE;

  prep        <<<dim3(3072),      256, 0, stream>>>(X, Wq, Wk, Wv, Wo, XbVh, WT);
  gemm_qkv128 <<<dim3(8, 64, 3),  256, 0, stream>>>(XbVh, WT, Qb, Kb, Vt);
  flash_attn  <<<dim3(32, 16),    512, 0, stream>>>(Qb, Kb, Vt, XbVh);
  gemm_proj128<<<dim3(16, 64),    256, 0, stream>>>(XbVh, WT + 3 * (size_t)DM * DM,
                                                    bo, out);
}